// Round 5
// baseline (467.700 us; speedup 1.0000x reference)
//
#include <hip/hip_runtime.h>

// Problem constants
#define S_LEN 2048
#define NH    16
#define HD    64
#define EMB   1024
#define NB    4
#define MROWS (NB * S_LEN)   // 8192

typedef __attribute__((ext_vector_type(8))) short  short8;   // 8 x bf16 bits (4 VGPRs)
typedef __attribute__((ext_vector_type(4))) float  float4_t; // MFMA C/D frag
typedef __attribute__((ext_vector_type(4))) int    int4_t;   // 16B int vector
union U8 { int4_t i; short8 s; };

__device__ __forceinline__ unsigned short f2bf(float f) {
    unsigned int x = __float_as_uint(f);
    unsigned int r = (x + 0x7fffu + ((x >> 16) & 1u)) >> 16;   // RNE
    return (unsigned short)r;
}

typedef const __attribute__((address_space(1))) unsigned int* gas_ptr;
typedef __attribute__((address_space(3))) unsigned int*       las_ptr;
__device__ __forceinline__ void gld_lds16(const void* g, void* l) {
    __builtin_amdgcn_global_load_lds((gas_ptr)g, (las_ptr)l, 16, 0, 0);
}

// ---------------------------------------------------------------------------
// elementwise fp32 -> bf16 (x), 2 elems/thread
// ---------------------------------------------------------------------------
__global__ void cvt_f32_bf16(const float* __restrict__ in,
                             unsigned short* __restrict__ out, int n2) {
    int i = blockIdx.x * blockDim.x + threadIdx.x;
    if (i < n2) {
        float2 v = ((const float2*)in)[i];
        ushort2 o; o.x = f2bf(v.x); o.y = f2bf(v.y);
        ((ushort2*)out)[i] = o;
    }
}

// ---------------------------------------------------------------------------
// fp32 transpose + convert: out_bf16[C][R] = in_f32[R][C]
// ---------------------------------------------------------------------------
__global__ void transpose_f32_bf16(const float* __restrict__ in,
                                   unsigned short* __restrict__ out, int R, int C) {
    __shared__ float tile[32][33];
    int n0 = blockIdx.x * 32, r0 = blockIdx.y * 32;
    int tx = threadIdx.x, ty = threadIdx.y;     // (32,8)
#pragma unroll
    for (int i = 0; i < 4; ++i)
        tile[ty + i * 8][tx] = in[(size_t)(r0 + ty + i * 8) * C + n0 + tx];
    __syncthreads();
#pragma unroll
    for (int i = 0; i < 4; ++i)
        out[(size_t)(n0 + ty + i * 8) * R + r0 + tx] = f2bf(tile[tx][ty + i * 8]);
}

// ---------------------------------------------------------------------------
// GEMM1: qkv = Xb[8192,1024] @ WqkvT[3072,1024]^T + bqkv(f32)
// epilogue scatters to Q[B,H,S,D], K[B,H,S,D], VT[B,H,D,S]  (all bf16)
// ---------------------------------------------------------------------------
__global__ __launch_bounds__(256) void gemm_qkv(
    const unsigned short* __restrict__ X,
    const unsigned short* __restrict__ WT,
    const float* __restrict__ bias,
    unsigned short* __restrict__ Qb,
    unsigned short* __restrict__ Kb,
    unsigned short* __restrict__ VTb)
{
    __shared__ alignas(16) unsigned short As[128 * 32];
    __shared__ alignas(16) unsigned short Bs[128 * 32];
    const int K = 1024;
    int t = threadIdx.x;
    int wave = t >> 6, lane = t & 63, quad = lane >> 4, l = lane & 15;
    int bm = blockIdx.x * 128, bn = blockIdx.y * 128;
    int wm = (wave >> 1) * 64, wn = (wave & 1) * 64;

    float4_t z = {0.f, 0.f, 0.f, 0.f};
    float4_t acc[4][4];
#pragma unroll
    for (int i = 0; i < 4; ++i)
#pragma unroll
        for (int j = 0; j < 4; ++j) acc[i][j] = z;

    for (int kt = 0; kt < K / 32; ++kt) {
        int k0 = kt * 32;
        if (kt) __syncthreads();
#pragma unroll
        for (int it = 0; it < 2; ++it) {
            int c = t + 256 * it;
            int row = c >> 2, col = (c & 3) * 8;
            gld_lds16(&X [(size_t)(bm + row) * K + k0 + col], &As[c * 8]);
            gld_lds16(&WT[(size_t)(bn + row) * K + k0 + col], &Bs[c * 8]);
        }
        __syncthreads();
        short8 af[4], bfr[4];
#pragma unroll
        for (int i = 0; i < 4; ++i)
            af[i] = *(const short8*)&As[(wm + i * 16 + l) * 32 + quad * 8];
#pragma unroll
        for (int j = 0; j < 4; ++j)
            bfr[j] = *(const short8*)&Bs[(wn + j * 16 + l) * 32 + quad * 8];
#pragma unroll
        for (int i = 0; i < 4; ++i)
#pragma unroll
            for (int j = 0; j < 4; ++j)
                acc[i][j] = __builtin_amdgcn_mfma_f32_16x16x32_bf16(
                    af[i], bfr[j], acc[i][j], 0, 0, 0);
    }
#pragma unroll
    for (int j = 0; j < 4; ++j) {
        int gc = bn + wn + j * 16 + l;
        float bv = bias[gc];
        int which = gc >> 10, rem = gc & 1023;
        int h = rem >> 6, d = rem & 63;
        if (which == 2) {
            int bb = bm >> 11;
            size_t rowbase = ((size_t)(bb * NH + h) * HD + d) * S_LEN;
#pragma unroll
            for (int i = 0; i < 4; ++i) {
                unsigned int u0 = __float_as_uint(acc[i][j][0] + bv) + 0x8000u;
                unsigned int u1 = __float_as_uint(acc[i][j][1] + bv) + 0x8000u;
                unsigned int u2 = __float_as_uint(acc[i][j][2] + bv) + 0x8000u;
                unsigned int u3 = __float_as_uint(acc[i][j][3] + bv) + 0x8000u;
                uint2 vv;
                vv.x = __builtin_amdgcn_perm(u1, u0, 0x07060302u);
                vv.y = __builtin_amdgcn_perm(u3, u2, 0x07060302u);
                int s0 = (bm + wm + i * 16 + quad * 4) & 2047;
                *(uint2*)&VTb[rowbase + s0] = vv;
            }
        } else {
#pragma unroll
            for (int i = 0; i < 4; ++i)
#pragma unroll
                for (int r = 0; r < 4; ++r) {
                    int gr = bm + wm + i * 16 + quad * 4 + r;
                    int b = gr >> 11, s = gr & 2047;
                    unsigned short ov = f2bf(acc[i][j][r] + bv);
                    size_t bh2 = (size_t)(b * NH + h);
                    if (which == 0) Qb[(bh2 * S_LEN + s) * HD + d] = ov;
                    else            Kb[(bh2 * S_LEN + s) * HD + d] = ov;
                }
        }
    }
}

// ---------------------------------------------------------------------------
// Flash attention (causal), barrier-free, transposed-score formulation,
// SOFTWARE-PIPELINED: two named KV register buffers; loads for tile kt+1
// are issued before tile kt's consumers wait (vmcnt(N>0) pattern).
// Wave = 32 queries of chunk pi AND 32 queries of mirror chunk (63-pi).
// ---------------------------------------------------------------------------
struct KV {
    short8 k0[4], k1[4];       // K A-fragments, two d-halves
    uint2  vlo[2][4], vhi[2][4]; // V B-fragment 8B pieces
};

__global__ __launch_bounds__(256, 2) void flash_attn(
    const unsigned short* __restrict__ Qb,
    const unsigned short* __restrict__ Kb,
    const unsigned short* __restrict__ VTb,
    unsigned short* __restrict__ AO)
{
    __shared__ alignas(16) unsigned short stg[4][16 * 68];  // per-wave O staging

    int t = threadIdx.x, wave = t >> 6, lane = t & 63, quad = lane >> 4, cl = lane & 15;
    int blk = blockIdx.x;
    int g = blk >> 3;
    int bh = (blk & 7) + 8 * (g & 7);    // XCD-pinned heads
    int pi = (g >> 3) * 4 + wave;        // 0..31 pair index
    int b = bh >> 4, h = bh & 15;
    int qbA = 32 * pi, qbB = 32 * (63 - pi);
    int nktA = ((qbA + 31) >> 6) + 1, nktB = ((qbB + 31) >> 6) + 1;

    const unsigned short* Qbase = Qb  + (size_t)bh * S_LEN * HD;
    const unsigned short* Kbase = Kb  + (size_t)bh * S_LEN * HD;
    const unsigned short* Vbase = VTb + (size_t)bh * HD * S_LEN;

    float4_t z = {0.f, 0.f, 0.f, 0.f};
    short8 bQA[2][2], bQB[2][2];
#pragma unroll
    for (int qt = 0; qt < 2; ++qt)
#pragma unroll
        for (int hh = 0; hh < 2; ++hh) {
            bQA[qt][hh] = *(const short8*)&Qbase[(size_t)(qbA + qt * 16 + cl) * HD + hh * 32 + quad * 8];
            bQB[qt][hh] = *(const short8*)&Qbase[(size_t)(qbB + qt * 16 + cl) * HD + hh * 32 + quad * 8];
        }

    float4_t accA[2][4], accB[2][4];
#pragma unroll
    for (int qt = 0; qt < 2; ++qt)
#pragma unroll
        for (int nb = 0; nb < 4; ++nb) { accA[qt][nb] = z; accB[qt][nb] = z; }
    float psA[2] = {0.f, 0.f}, psB[2] = {0.f, 0.f};

    auto loadKV = [&](int kt, KV& kv) {
        int key0 = kt << 6;
#pragma unroll
        for (int t4 = 0; t4 < 4; ++t4) {
            const unsigned short* kr = &Kbase[(size_t)(key0 + t4 * 16 + cl) * HD + quad * 8];
            kv.k0[t4] = *(const short8*)kr;
            kv.k1[t4] = *(const short8*)(kr + 32);
        }
#pragma unroll
        for (int p = 0; p < 2; ++p)
#pragma unroll
            for (int nb = 0; nb < 4; ++nb) {
                const unsigned short* vr = &Vbase[(size_t)(nb * 16 + cl) * S_LEN + key0 + p * 32 + quad * 4];
                kv.vlo[p][nb] = *(const uint2*)vr;
                kv.vhi[p][nb] = *(const uint2*)(vr + 16);
            }
    };

    auto chunk = [&](int kt, int qb, int nkt, short8 (&bQ)[2][2],
                     float4_t (&acc)[2][4], float (&ps)[2], KV& kv) {
        if (kt >= nkt) return;
        int key0 = kt << 6;
        bool diag = (kt == nkt - 1);
#pragma unroll
        for (int qt = 0; qt < 2; ++qt) {
            unsigned int pk[4][2];
#pragma unroll
            for (int t4 = 0; t4 < 4; ++t4) {
                float4_t st = __builtin_amdgcn_mfma_f32_16x16x32_bf16(
                    kv.k1[t4], bQ[qt][1],
                    __builtin_amdgcn_mfma_f32_16x16x32_bf16(kv.k0[t4], bQ[qt][0], z, 0, 0, 0),
                    0, 0, 0);
                unsigned int u[4];
#pragma unroll
                for (int r = 0; r < 4; ++r) {
                    // exp(s/8) = exp2(s * 0.125*log2e) -> bare v_exp_f32
                    float e = exp2f(st[r] * 0.18033688f);
                    if (diag) {
                        int key = key0 + t4 * 16 + quad * 4 + r;
                        e = (key <= qb + qt * 16 + cl) ? e : 0.f;
                    }
                    ps[qt] += e;
                    u[r] = __float_as_uint(e) + 0x8000u;
                }
                pk[t4][0] = __builtin_amdgcn_perm(u[1], u[0], 0x07060302u);
                pk[t4][1] = __builtin_amdgcn_perm(u[3], u[2], 0x07060302u);
            }
#pragma unroll
            for (int p = 0; p < 2; ++p) {
                U8 a; a.i = (int4_t){(int)pk[2 * p][0], (int)pk[2 * p][1],
                                     (int)pk[2 * p + 1][0], (int)pk[2 * p + 1][1]};
#pragma unroll
                for (int nb = 0; nb < 4; ++nb) {
                    U8 bb; bb.i = (int4_t){(int)kv.vlo[p][nb].x, (int)kv.vlo[p][nb].y,
                                           (int)kv.vhi[p][nb].x, (int)kv.vhi[p][nb].y};
                    acc[qt][nb] = __builtin_amdgcn_mfma_f32_16x16x32_bf16(
                        a.s, bb.s, acc[qt][nb], 0, 0, 0);
                }
            }
        }
    };

    auto step = [&](int kt, KV& kv) {
        chunk(kt, qbA, nktA, bQA, accA, psA, kv);
        chunk(kt, qbB, nktB, bQB, accB, psB, kv);
    };

    KV kva, kvb;
    loadKV(0, kva);
    for (int kt = 0; kt < nktB; ) {
        if (kt + 1 < nktB) loadKV(kt + 1, kvb);   // prefetch before kva's waits
        step(kt, kva);
        ++kt;
        if (kt >= nktB) break;
        if (kt + 1 < nktB) loadKV(kt + 1, kva);   // prefetch before kvb's waits
        step(kt, kvb);
        ++kt;
    }

    auto flush = [&](int qb, float4_t (&acc)[2][4], float (&ps)[2]) {
#pragma unroll
        for (int qt = 0; qt < 2; ++qt) {
            float s = ps[qt];
            s += __shfl_xor(s, 16);
            s += __shfl_xor(s, 32);
            float inv = 1.f / s;                 // full sum for query qb+qt*16+cl
            float fr[4];
#pragma unroll
            for (int r = 0; r < 4; ++r) fr[r] = __shfl(inv, quad * 4 + r);
#pragma unroll
            for (int nb = 0; nb < 4; ++nb)
#pragma unroll
                for (int r = 0; r < 4; ++r) {
                    unsigned int u = __float_as_uint(acc[qt][nb][r] * fr[r]) + 0x8000u;
                    stg[wave][(quad * 4 + r) * 68 + nb * 16 + cl] = (unsigned short)(u >> 16);
                }
#pragma unroll
            for (int pass = 0; pass < 4; ++pass) {
                int idx = pass * 64 + lane;
                int row = idx >> 4, part = idx & 15;
                ushort4 v = *(const ushort4*)&stg[wave][row * 68 + part * 4];
                *(ushort4*)&AO[((size_t)b * S_LEN + qb + qt * 16 + row) * EMB + h * HD + part * 4] = v;
            }
        }
    };
    flush(qbA, accA, psA);
    flush(qbB, accB, psB);
}

// ---------------------------------------------------------------------------
// GEMM2: out_f32 = AO[8192,1024]bf16 @ WoutT[1024,1024]^T + bout(f32)
// ---------------------------------------------------------------------------
__global__ __launch_bounds__(256) void gemm_out(
    const unsigned short* __restrict__ A,
    const unsigned short* __restrict__ WT,
    const float* __restrict__ bias,
    float* __restrict__ out)
{
    __shared__ alignas(16) unsigned short As[128 * 32];
    __shared__ alignas(16) unsigned short Bs[128 * 32];
    const int K = 1024;
    int t = threadIdx.x;
    int wave = t >> 6, lane = t & 63, quad = lane >> 4, l = lane & 15;
    int bm = blockIdx.x * 128, bn = blockIdx.y * 128;
    int wm = (wave >> 1) * 64, wn = (wave & 1) * 64;

    float4_t z = {0.f, 0.f, 0.f, 0.f};
    float4_t acc[4][4];
#pragma unroll
    for (int i = 0; i < 4; ++i)
#pragma unroll
        for (int j = 0; j < 4; ++j) acc[i][j] = z;

    for (int kt = 0; kt < K / 32; ++kt) {
        int k0 = kt * 32;
        if (kt) __syncthreads();
#pragma unroll
        for (int it = 0; it < 2; ++it) {
            int c = t + 256 * it;
            int row = c >> 2, col = (c & 3) * 8;
            gld_lds16(&A [(size_t)(bm + row) * K + k0 + col], &As[c * 8]);
            gld_lds16(&WT[(size_t)(bn + row) * K + k0 + col], &Bs[c * 8]);
        }
        __syncthreads();
        short8 af[4], bfr[4];
#pragma unroll
        for (int i = 0; i < 4; ++i)
            af[i] = *(const short8*)&As[(wm + i * 16 + l) * 32 + quad * 8];
#pragma unroll
        for (int j = 0; j < 4; ++j)
            bfr[j] = *(const short8*)&Bs[(wn + j * 16 + l) * 32 + quad * 8];
#pragma unroll
        for (int i = 0; i < 4; ++i)
#pragma unroll
            for (int j = 0; j < 4; ++j)
                acc[i][j] = __builtin_amdgcn_mfma_f32_16x16x32_bf16(
                    af[i], bfr[j], acc[i][j], 0, 0, 0);
    }
#pragma unroll
    for (int j = 0; j < 4; ++j) {
        int gc = bn + wn + j * 16 + l;
        float bv = bias[gc];
#pragma unroll
        for (int i = 0; i < 4; ++i) {
#pragma unroll
            for (int r = 0; r < 4; ++r) {
                int gr = bm + wm + i * 16 + quad * 4 + r;
                out[(size_t)gr * EMB + gc] = acc[i][j][r] + bv;
            }
        }
    }
}

// ---------------------------------------------------------------------------
extern "C" void kernel_launch(void* const* d_in, const int* in_sizes, int n_in,
                              void* d_out, int out_size, void* d_ws, size_t ws_size,
                              hipStream_t stream) {
    const float* x    = (const float*)d_in[0];
    // d_in[1] = causal mask (int32 tril) -- implemented analytically, not read
    const float* Wqkv = (const float*)d_in[2];
    const float* bqkv = (const float*)d_in[3];
    const float* Wout = (const float*)d_in[4];
    const float* bout = (const float*)d_in[5];
    float* out = (float*)d_out;

    // workspace (bf16): Q 16MB | K 16MB | VT 16MB | Xb/AO 16MB (aliased) |
    // WqkvT 6MB | WoutT 2MB = 72MB
    char* ws = (char*)d_ws;
    const size_t SZ = (size_t)NB * NH * S_LEN * HD * 2;  // 16 MiB
    unsigned short* Qb    = (unsigned short*)(ws);
    unsigned short* Kb    = (unsigned short*)(ws + SZ);
    unsigned short* VTb   = (unsigned short*)(ws + 2 * SZ);
    unsigned short* Xb    = (unsigned short*)(ws + 3 * SZ);
    unsigned short* AO    = (unsigned short*)(ws + 3 * SZ);  // alias with Xb
    unsigned short* WqkvT = (unsigned short*)(ws + 4 * SZ);
    unsigned short* WoutT = (unsigned short*)(ws + 4 * SZ + (size_t)3 * EMB * EMB * 2);

    int n2 = MROWS * EMB / 2;
    cvt_f32_bf16<<<dim3((n2 + 255) / 256), 256, 0, stream>>>(x, Xb, n2);
    dim3 tb(32, 8);
    transpose_f32_bf16<<<dim3(3 * EMB / 32, EMB / 32), tb, 0, stream>>>(Wqkv, WqkvT, EMB, 3 * EMB);
    transpose_f32_bf16<<<dim3(EMB / 32, EMB / 32), tb, 0, stream>>>(Wout, WoutT, EMB, EMB);
    gemm_qkv<<<dim3(MROWS / 128, 3 * EMB / 128), 256, 0, stream>>>(Xb, WqkvT, bqkv, Qb, Kb, VTb);
    flash_attn<<<dim3(512), 256, 0, stream>>>(Qb, Kb, VTb, AO);
    gemm_out<<<dim3(MROWS / 128, EMB / 128), 256, 0, stream>>>(AO, WoutT, bout, out);
}